// Round 6
// baseline (202.345 us; speedup 1.0000x reference)
//
#include <hip/hip_runtime.h>

typedef __attribute__((ext_vector_type(8))) short short8;
typedef __attribute__((ext_vector_type(4))) float f32x4;
typedef unsigned short u16;
typedef unsigned int u32;
typedef unsigned long long u64;

#define TAU_F 0.3f

__device__ __forceinline__ u16 f2bf(float f){
  u32 u = __float_as_uint(f);
  u32 r = u + 0x7FFFu + ((u >> 16) & 1u);
  return (u16)(r >> 16);
}
__device__ __forceinline__ float bf2f(u16 v){
  return __uint_as_float(((u32)v) << 16);
}

typedef __attribute__((address_space(1))) const u32 glb_u32;
typedef __attribute__((address_space(3))) u32 lds_u32;
__device__ __forceinline__ void async_lds16(const void* g, void* l){
  __builtin_amdgcn_global_load_lds((glb_u32*)g, (lds_u32*)l, 16, 0, 0);
}

// ---------------- compaction: per-batch valid-node count + index list --------
__global__ __launch_bounds__(1024)
void compact_kernel(const int* __restrict__ mask, int* __restrict__ cnt, int* __restrict__ idx)
{
  __shared__ int wtot[16];
  __shared__ int woff[16];
  const int b = blockIdx.x, t = threadIdx.x;
  const int w = t >> 6, lane = t & 63;
  const int m = mask[(b << 10) + t];
  const u64 bal = __ballot(m != 0);
  const int pos = __popcll(bal & ((1ull << lane) - 1ull));
  if (lane == 0) wtot[w] = __popcll(bal);
  __syncthreads();
  if (t == 0) {
    int acc = 0;
    for (int i = 0; i < 16; i++) { woff[i] = acc; acc += wtot[i]; }
    cnt[b] = acc;
  }
  __syncthreads();
  if (m) idx[(b << 10) + woff[w] + pos] = t;
}

// ------- bf16 NT GEMM, 64x64 tile, BK=64, double-buffered, XOR-swizzled -------
// MODE 0: adj-byte epilogue (sim > TAU, guarded to [0,cnt)^2)
// MODE 1: gT store  (out[(b*128+c)*1024 + l] = bf16(acc)), b=row>>10, l=row&1023
// MODE 2: tanh(acc + bvec[col]) -> bf16, ldc=512
template<int MODE>
__global__ __launch_bounds__(256)
void gemm_nt(const u16* __restrict__ A, const u16* __restrict__ B,
             int lda, int ldb, int K, long sA, long sB,
             void* __restrict__ outp,
             const int* __restrict__ cnt,
             const float* __restrict__ bvec)
{
  __shared__ u16 lA[2][64*64];
  __shared__ u16 lB[2][64*64];
  const int t = threadIdx.x;
  const int w = t >> 6, lane = t & 63;
  const int bz = blockIdx.z;
  const int i0 = blockIdx.y * 64, n0 = blockIdx.x * 64;
  int cb = 0;
  if (MODE == 0) {
    cb = cnt[bz];
    if (i0 >= cb || n0 >= cb) return;
  } else {
    if ((i0 & 1023) >= cnt[i0 >> 10]) return;
  }
  const u16* Ab = A + (long)bz * sA;
  const u16* Bb = B + (long)bz * sB;
  const int wr = w >> 1, wc = w & 1;
  // staging: thread t covers rows (t>>3) and (t>>3)+32, col-group t&7 (8 elems)
  const int srow = t >> 3, scg = t & 7;
  const int sc0 = ((scg ^ (srow & 7)) << 3);      // swizzled source col offset
  const long arow0 = (long)(i0 + srow) * lda, arow1 = (long)(i0 + srow + 32) * lda;
  const long brow0 = (long)(n0 + srow) * ldb, brow1 = (long)(n0 + srow + 32) * ldb;
  // fragment read offsets (swizzle-aware)
  const int rA = lane & 15, kg = lane >> 4;
  const int sw = rA & 7;
  const int off0 = ((kg ^ sw) << 3);              // kk = 0
  const int off1 = (((4 + kg) ^ sw) << 3);        // kk = 1
  const int rowA0 = (wr*32 + rA) * 64, rowA1 = (wr*32 + 16 + rA) * 64;
  const int rowB0 = (wc*32 + rA) * 64, rowB1 = (wc*32 + 16 + rA) * 64;
  f32x4 acc[2][2] = {};

  auto stage = [&](int buf, int kt) {
    async_lds16(Ab + arow0 + kt + sc0, &lA[buf][t*8]);
    async_lds16(Ab + arow1 + kt + sc0, &lA[buf][2048 + t*8]);
    async_lds16(Bb + brow0 + kt + sc0, &lB[buf][t*8]);
    async_lds16(Bb + brow1 + kt + sc0, &lB[buf][2048 + t*8]);
  };
  auto compute = [&](int buf) {
    short8 a00 = *(const short8*)&lA[buf][rowA0 + off0];
    short8 a01 = *(const short8*)&lA[buf][rowA0 + off1];
    short8 a10 = *(const short8*)&lA[buf][rowA1 + off0];
    short8 a11 = *(const short8*)&lA[buf][rowA1 + off1];
    short8 b00 = *(const short8*)&lB[buf][rowB0 + off0];
    short8 b01 = *(const short8*)&lB[buf][rowB0 + off1];
    short8 b10 = *(const short8*)&lB[buf][rowB1 + off0];
    short8 b11 = *(const short8*)&lB[buf][rowB1 + off1];
    acc[0][0] = __builtin_amdgcn_mfma_f32_16x16x32_bf16(a00, b00, acc[0][0], 0, 0, 0);
    acc[0][1] = __builtin_amdgcn_mfma_f32_16x16x32_bf16(a00, b10, acc[0][1], 0, 0, 0);
    acc[1][0] = __builtin_amdgcn_mfma_f32_16x16x32_bf16(a10, b00, acc[1][0], 0, 0, 0);
    acc[1][1] = __builtin_amdgcn_mfma_f32_16x16x32_bf16(a10, b10, acc[1][1], 0, 0, 0);
    acc[0][0] = __builtin_amdgcn_mfma_f32_16x16x32_bf16(a01, b01, acc[0][0], 0, 0, 0);
    acc[0][1] = __builtin_amdgcn_mfma_f32_16x16x32_bf16(a01, b11, acc[0][1], 0, 0, 0);
    acc[1][0] = __builtin_amdgcn_mfma_f32_16x16x32_bf16(a11, b01, acc[1][0], 0, 0, 0);
    acc[1][1] = __builtin_amdgcn_mfma_f32_16x16x32_bf16(a11, b11, acc[1][1], 0, 0, 0);
  };

  const int nt = K >> 6;
  stage(0, 0);
  __syncthreads();
  int cur = 0;
  for (int kt = 1; kt < nt; kt++) {
    stage(cur ^ 1, kt << 6);
    compute(cur);
    __syncthreads();
    cur ^= 1;
  }
  compute(cur);

#pragma unroll
  for (int m = 0; m < 2; m++) {
    const int gi0 = i0 + wr*32 + m*16 + kg*4;
#pragma unroll
    for (int n = 0; n < 2; n++) {
      const int gj = n0 + wc*32 + n*16 + rA;
#pragma unroll
      for (int r = 0; r < 4; r++) {
        const int gi = gi0 + r;
        const float c = acc[m][n][r];
        if (MODE == 0) {
          if (gi < cb && gj < cb)
            ((unsigned char*)outp)[((long)bz << 20) + ((long)gi << 10) + gj] = (c > TAU_F) ? 1 : 0;
        } else if (MODE == 1) {
          const int b = gi >> 10, l = gi & 1023;
          ((u16*)outp)[(((long)(b*128 + gj)) << 10) + l] = f2bf(c);
        } else {
          ((u16*)outp)[(long)gi * 512 + gj] = f2bf(tanhf(c + bvec[gj]));
        }
      }
    }
  }
}

// ---------------- fused GAT attention, sparsity-skipping, compacted ----------
// Adjacency words masked against cb at load: the pad region of adj is NEVER
// read (no memset needed; stale/poison pad is harmless).
__global__ __launch_bounds__(256)
void gat_attn(const unsigned char* __restrict__ adj,
              const float* __restrict__ ald, const float* __restrict__ als,
              const u16* __restrict__ gT, const float* __restrict__ bias,
              const int* __restrict__ cnt,
              float* __restrict__ hf, u16* __restrict__ hall, int hall_off)
{
  __shared__ float red[4][16][132];
  __shared__ float ssumw[4][16];
  const int t = threadIdx.x, w = t >> 6, lane = t & 63;
  const int bz = blockIdx.y, i0 = blockIdx.x * 16;
  const int cb = cnt[bz];
  if (i0 >= cb) return;
  const int rr = lane & 15, kg = lane >> 4;
  const int r0 = i0 + rr;
  const float ald0 = ald[(bz << 10) + r0];
  const unsigned char* arow = adj + ((long)bz << 20) + ((long)r0 << 10);
  const float* als_b = als + (bz << 10);
  const u16* gTb = gT + ((long)bz << 17);
  float s0 = 0.f;
  f32x4 acc[8] = {};
  const int jbase = w * 256 + kg * 8;

  u64 aw[8];
#pragma unroll
  for (int it = 0; it < 8; it++) {
    const int jl = jbase + it*32;
    u64 a = 0;
    if (jl < cb) {
      a = *(const u64*)(arow + jl);
      const int rem = cb - jl;
      if (rem < 8) a &= (1ull << (rem * 8)) - 1ull;   // keep only cols < cb
    }
    aw[it] = a;
  }

#pragma unroll
  for (int it = 0; it < 8; it++) {
    const u64 a0 = aw[it];
    if (__any(a0 != 0ull)) {
      const int jl = jbase + it*32;
      const float4 f0 = *(const float4*)(als_b + jl);
      const float4 f1 = *(const float4*)(als_b + jl + 4);
      const float sv[8] = {f0.x, f0.y, f0.z, f0.w, f1.x, f1.y, f1.z, f1.w};
      short8 pa;
#pragma unroll
      for (int e = 0; e < 8; e++) {
        float x = ald0 + sv[e];
        x = x > 0.f ? x : 0.2f * x;
        const float p = ((a0 >> (8*e)) & 255ull) ? __expf(x) : 0.f;
        s0 += p;
        pa[e] = (short)f2bf(p);
      }
#pragma unroll
      for (int nf = 0; nf < 8; nf++) {
        const short8 b = *(const short8*)&gTb[(long)(nf*16 + rr) * 1024 + jl];
        acc[nf] = __builtin_amdgcn_mfma_f32_16x16x32_bf16(pa, b, acc[nf], 0, 0, 0);
      }
    }
  }

  s0 += __shfl_xor(s0, 16, 64);
  s0 += __shfl_xor(s0, 32, 64);
  if (lane < 16) ssumw[w][lane] = s0;
#pragma unroll
  for (int nf = 0; nf < 8; nf++)
#pragma unroll
    for (int rg = 0; rg < 4; rg++)
      red[w][kg*4 + rg][nf*16 + rr] = acc[nf][rg];
  __syncthreads();

  const int r = t >> 4, c0 = (t & 15) * 8;
  const float sm = ssumw[0][r] + ssumw[1][r] + ssumw[2][r] + ssumw[3][r];
  const float inv = sm > 0.f ? 1.f / sm : 0.f;
  const long gi = ((long)bz << 10) + i0 + r;
  float* hrow = hf + gi * 128;
  u16* orow = hall + gi * 1024 + hall_off;
#pragma unroll
  for (int q = 0; q < 8; q++) {
    const int c = c0 + q;
    float v = (red[0][r][c] + red[1][r][c] + red[2][r][c] + red[3][r][c]) * inv + bias[c];
    v = v > 0.f ? v : 0.f;
    hrow[c] = v;
    orow[c] = f2bf(v);
  }
}

// ---------------- small kernels ----------------
__global__ __launch_bounds__(256)
void hn_kernel(const float* __restrict__ hidden, const int* __restrict__ cnt,
               const int* __restrict__ idx, u16* __restrict__ hnc, u16* __restrict__ hallc)
{
  const int gr = blockIdx.x * 4 + (threadIdx.x >> 6);
  const int b = gr >> 10, c = gr & 1023;
  const int lane = threadIdx.x & 63;
  if (c >= cnt[b]) return;
  const int l = idx[gr];
  const float* h = hidden + (long)((b << 10) + l) * 768;
  float x[12]; float ss = 0.f;
#pragma unroll
  for (int k = 0; k < 12; k++) { x[k] = h[k*64 + lane]; ss += x[k]*x[k]; }
#pragma unroll
  for (int o = 32; o > 0; o >>= 1) ss += __shfl_xor(ss, o, 64);
  const float inv = 1.f / fmaxf(sqrtf(ss), 1e-8f);
#pragma unroll
  for (int k = 0; k < 12; k++) {
    hnc[(long)gr*768   + k*64 + lane] = f2bf(x[k] * inv);
    hallc[(long)gr*1024 + k*64 + lane] = f2bf(x[k]);
  }
}

__global__ void transpose_bf(const float* __restrict__ in, u16* __restrict__ out, int K, int N)
{
  const int idx = blockIdx.x * 256 + threadIdx.x;
  if (idx >= K * N) return;
  const int k = idx / N, n = idx % N;
  out[(long)n * K + k] = f2bf(in[idx]);
}

__global__ void ae_kernel(const float* we0, const float* ao0, const float* we1, const float* ao1, float* out)
{
  __shared__ float s0[128], s1[128];
  const int t = threadIdx.x;
  s0[t] = we0[t] * ao0[t];
  s1[t] = we1[t] * ao1[t];
  __syncthreads();
  for (int o = 64; o > 0; o >>= 1) { if (t < o) { s0[t]+=s0[t+o]; s1[t]+=s1[t+o]; } __syncthreads(); }
  if (t == 0) { out[0] = s0[0]; out[1] = s1[0]; }
}

__global__ void al_kernel(const u16* __restrict__ gT,
                          const float* __restrict__ a_src, const float* __restrict__ a_dst,
                          const float* __restrict__ aeptr, const int* __restrict__ cnt,
                          float* __restrict__ als, float* __restrict__ ald)
{
  const int b = blockIdx.y;
  const int l = blockIdx.x * 256 + threadIdx.x;
  if (l >= cnt[b]) return;
  const u16* g = gT + ((long)b << 17) + l;
  float ss = 0.f, sd = 0.f;
#pragma unroll 4
  for (int c = 0; c < 128; c++) {
    const float v = bf2f(g[(long)c << 10]);
    ss += v * a_src[c];
    sd += v * a_dst[c];
  }
  als[(b << 10) + l] = ss;
  ald[(b << 10) + l] = sd + aeptr[0];
}

__global__ __launch_bounds__(256)
void gemv_scores(const u16* __restrict__ tb, const float* __restrict__ S2W,
                 const float* __restrict__ S2b, const int* __restrict__ cnt,
                 float* __restrict__ scores)
{
  const int row = blockIdx.x * 4 + (threadIdx.x >> 6);
  const int b = row >> 10, c = row & 1023;
  const int lane = threadIdx.x & 63;
  if (c >= cnt[b]) return;
  const short8 v = *(const short8*)&tb[(long)row * 512 + lane * 8];
  float s = 0.f;
#pragma unroll
  for (int i = 0; i < 8; i++) s += bf2f((u16)v[i]) * S2W[lane*8 + i];
#pragma unroll
  for (int o = 32; o > 0; o >>= 1) s += __shfl_xor(s, o, 64);
  if (lane == 0) scores[row] = s + S2b[0];
}

__global__ void softmax_w(const float* __restrict__ scores, const int* __restrict__ cnt,
                          float* __restrict__ wts)
{
  __shared__ float wsum[4];
  const int b = blockIdx.x, t = threadIdx.x;
  const int cb = cnt[b];
  float e[4]; float part = 0.f;
#pragma unroll
  for (int q = 0; q < 4; q++) {
    const int l = q*256 + t;
    const float ex = (l < cb) ? __expf(scores[(b<<10) + l]) : 0.f;
    e[q] = ex; part += ex;
  }
#pragma unroll
  for (int o = 32; o > 0; o >>= 1) part += __shfl_xor(part, o, 64);
  if ((t & 63) == 0) wsum[t >> 6] = part;
  __syncthreads();
  const float total = wsum[0] + wsum[1] + wsum[2] + wsum[3];
  const float inv = 1.f / fmaxf(total, 1e-16f);
#pragma unroll
  for (int q = 0; q < 4; q++) wts[(b<<10) + q*256 + t] = e[q] * inv;
}

__global__ void zero_out_k(float* out){ out[blockIdx.x*256 + threadIdx.x] = 0.f; }

__global__ __launch_bounds__(256)
void pooled_kernel(const float* __restrict__ hidden, const float* __restrict__ h1f,
                   const float* __restrict__ h2f, const float* __restrict__ wts,
                   const int* __restrict__ cnt, const int* __restrict__ idx,
                   float* __restrict__ out)
{
  const int b = blockIdx.y, l0 = blockIdx.x * 64, t = threadIdx.x;
  const int cb = cnt[b];
  if (l0 >= cb) return;
  const int lim = min(64, cb - l0);
  float a0=0.f, a1=0.f, a2=0.f, a3=0.f;
  for (int l = 0; l < lim; l++) {
    const int gl = (b << 10) + l0 + l;
    const float wv = wts[gl];
    const float* hr = hidden + (long)((b << 10) + idx[gl]) * 768;
    a0 += wv * hr[t];
    a1 += wv * hr[256 + t];
    a2 += wv * hr[512 + t];
    const float v3 = (t < 128) ? h1f[(long)gl*128 + t] : h2f[(long)gl*128 + (t - 128)];
    a3 += wv * v3;
  }
  atomicAdd(&out[(b<<10) + t],        a0);
  atomicAdd(&out[(b<<10) + 256 + t],  a1);
  atomicAdd(&out[(b<<10) + 512 + t],  a2);
  atomicAdd(&out[(b<<10) + 768 + t],  a3);
}

// ---------------- launch ----------------
extern "C" void kernel_launch(void* const* d_in, const int* in_sizes, int n_in,
                              void* d_out, int out_size, void* d_ws, size_t ws_size,
                              hipStream_t stream)
{
  const float* hidden = (const float*)d_in[0];
  const int*   mask   = (const int*)d_in[1];
  const float* W0     = (const float*)d_in[2];
  const float* asrc0  = (const float*)d_in[3];
  const float* adst0  = (const float*)d_in[4];
  const float* wed0   = (const float*)d_in[5];
  const float* aed0   = (const float*)d_in[6];
  const float* bias0  = (const float*)d_in[7];
  const float* W1     = (const float*)d_in[8];
  const float* asrc1  = (const float*)d_in[9];
  const float* adst1  = (const float*)d_in[10];
  const float* wed1   = (const float*)d_in[11];
  const float* aed1   = (const float*)d_in[12];
  const float* bias1  = (const float*)d_in[13];
  const float* S1W    = (const float*)d_in[14];
  const float* S1b    = (const float*)d_in[15];
  const float* S2W    = (const float*)d_in[16];
  const float* S2b    = (const float*)d_in[17];
  float* out = (float*)d_out;

  char* ws = (char*)d_ws;
  u16* hallc = (u16*)(ws + 0);                    // 16384x1024 bf16 compacted (33554432 B)
  u16* hnc  = (u16*)(ws + 33554432);              // 16384x768 bf16 compacted (25165824 B), reused as tb
  u16* tb   = hnc;                                // tanh buf 16384x512 bf16 (16 MB), written after hnc last read
  unsigned char* adj = (unsigned char*)(ws + 58720256); // 16x1024x1024 (16777216 B)
  u16* gt   = (u16*)(ws + 75497472);              // 16x128x1024 bf16 (4194304 B)
  u16* w0t  = (u16*)(ws + 79691776);              // 128x768
  u16* w1t  = (u16*)(ws + 79888384);              // 128x128
  u16* s1t  = (u16*)(ws + 79921152);              // 512x1024
  float* ald = (float*)(ws + 80969728);           // 16x1024
  float* als = (float*)(ws + 81035264);           // 16x1024
  float* h1f = (float*)(ws + 81100800);           // 16x1024x128 f32 compacted
  float* h2f = (float*)(ws + 89489408);           // 16x1024x128 f32 compacted
  float* scores = (float*)(ws + 97878016);        // 16x1024
  float* wts    = (float*)(ws + 97943552);        // 16x1024
  float* aeb    = (float*)(ws + 98009088);        // 2 floats
  int*   cnt    = (int*)(ws + 98009600);          // 16 ints
  int*   idxb   = (int*)(ws + 98010112);          // 16x1024 ints (65536 B)

  zero_out_k<<<64, 256, 0, stream>>>(out);
  ae_kernel<<<1, 128, 0, stream>>>(wed0, aed0, wed1, aed1, aeb);
  compact_kernel<<<16, 1024, 0, stream>>>(mask, cnt, idxb);
  transpose_bf<<<384,  256, 0, stream>>>(W0,  w0t, 768, 128);
  transpose_bf<<<64,   256, 0, stream>>>(W1,  w1t, 128, 128);
  transpose_bf<<<2048, 256, 0, stream>>>(S1W, s1t, 1024, 512);
  hn_kernel<<<4096, 256, 0, stream>>>(hidden, cnt, idxb, hnc, hallc);

  // adjacency in compacted space: sim > TAU on valid-node pairs
  gemm_nt<0><<<dim3(16,16,16), 256, 0, stream>>>(hnc, hnc, 768, 768, 768,
        (long)1024*768, (long)1024*768, adj, cnt, nullptr);

  // layer 0
  gemm_nt<1><<<dim3(2,256,1), 256, 0, stream>>>(hallc, w0t, 1024, 768, 768, 0, 0, gt, cnt, nullptr);
  al_kernel<<<dim3(4,16), 256, 0, stream>>>(gt, asrc0, adst0, aeb, cnt, als, ald);
  gat_attn<<<dim3(64,16), 256, 0, stream>>>(adj, ald, als, gt, bias0, cnt, h1f, hallc, 768);

  // layer 1
  gemm_nt<1><<<dim3(2,256,1), 256, 0, stream>>>(hallc + 768, w1t, 1024, 128, 128, 0, 0, gt, cnt, nullptr);
  al_kernel<<<dim3(4,16), 256, 0, stream>>>(gt, asrc1, adst1, aeb + 1, cnt, als, ald);
  gat_attn<<<dim3(64,16), 256, 0, stream>>>(adj, ald, als, gt, bias1, cnt, h2f, hallc, 896);

  // scorer
  gemm_nt<2><<<dim3(8,256,1), 256, 0, stream>>>(hallc, s1t, 1024, 1024, 1024, 0, 0, tb, cnt, S1b);
  gemv_scores<<<4096, 256, 0, stream>>>(tb, S2W, S2b, cnt, scores);
  softmax_w<<<16, 256, 0, stream>>>(scores, cnt, wts);
  pooled_kernel<<<dim3(16,16), 256, 0, stream>>>(hidden, h1f, h2f, wts, cnt, idxb, out);
}

// Round 7
// 181.195 us; speedup vs baseline: 1.1167x; 1.1167x over previous
//
#include <hip/hip_runtime.h>

typedef __attribute__((ext_vector_type(8))) short short8;
typedef __attribute__((ext_vector_type(4))) float f32x4;
typedef unsigned short u16;
typedef unsigned int u32;
typedef unsigned long long u64;

#define TAU_F 0.3f

__device__ __forceinline__ u16 f2bf(float f){
  u32 u = __float_as_uint(f);
  u32 r = u + 0x7FFFu + ((u >> 16) & 1u);
  return (u16)(r >> 16);
}
__device__ __forceinline__ float bf2f(u16 v){
  return __uint_as_float(((u32)v) << 16);
}

typedef __attribute__((address_space(1))) const u32 glb_u32;
typedef __attribute__((address_space(3))) u32 lds_u32;
__device__ __forceinline__ void async_lds16(const void* g, void* l){
  __builtin_amdgcn_global_load_lds((glb_u32*)g, (lds_u32*)l, 16, 0, 0);
}

// ---------------- merged preprocessing (one launch) --------------------------
// blocks [0,16): zero out | [16,32): zero scores | [32,128): W0^T
// [128,144): W1^T | [144,656): S1W^T | 656: ae | 657: u0/v0 | 658: u1/v1
// [659,675): per-batch compaction
__global__ __launch_bounds__(1024)
void pre_kernel(float* __restrict__ out, float* __restrict__ scores,
                const float* __restrict__ W0, u16* __restrict__ w0t,
                const float* __restrict__ W1, u16* __restrict__ w1t,
                const float* __restrict__ S1W, u16* __restrict__ s1t,
                const float* __restrict__ wed0, const float* __restrict__ aed0,
                const float* __restrict__ wed1, const float* __restrict__ aed1,
                float* __restrict__ aeb,
                const float* __restrict__ asrc0, const float* __restrict__ adst0,
                const float* __restrict__ asrc1, const float* __restrict__ adst1,
                float* __restrict__ u0, float* __restrict__ v0,
                float* __restrict__ u1, float* __restrict__ v1,
                const int* __restrict__ mask, int* __restrict__ cnt, int* __restrict__ idxb)
{
  __shared__ float lds[1024];
  const int blk = blockIdx.x, t = threadIdx.x;
  if (blk < 16) { out[blk*1024 + t] = 0.f; return; }
  if (blk < 32) { scores[(blk-16)*1024 + t] = 0.f; return; }
  if (blk < 128) { const int i = (blk-32)*1024 + t; if (i < 98304) { const int k = i >> 7, n = i & 127; w0t[n*768 + k] = f2bf(W0[i]); } return; }
  if (blk < 144) { const int i = (blk-128)*1024 + t; const int k = i >> 7, n = i & 127; w1t[n*128 + k] = f2bf(W1[i]); return; }
  if (blk < 656) { const int i = (blk-144)*1024 + t; const int k = i >> 9, n = i & 511; s1t[n*1024 + k] = f2bf(S1W[i]); return; }
  if (blk == 656) {
    if (t < 128) { lds[t] = wed0[t]*aed0[t]; lds[128+t] = wed1[t]*aed1[t]; }
    __syncthreads();
    for (int o = 64; o > 0; o >>= 1) { if (t < o) { lds[t] += lds[t+o]; lds[128+t] += lds[128+t+o]; } __syncthreads(); }
    if (t == 0) { aeb[0] = lds[0]; aeb[1] = lds[128]; }
    return;
  }
  if (blk == 657) {
    if (t < 768) {
      float su = 0.f, sv = 0.f;
      for (int c = 0; c < 128; c++) { const float w = W0[t*128 + c]; su += w*asrc0[c]; sv += w*adst0[c]; }
      u0[t] = su; v0[t] = sv;
    }
    return;
  }
  if (blk == 658) {
    if (t < 128) {
      float su = 0.f, sv = 0.f;
      for (int k = 0; k < 128; k++) { const float w = W1[k*128 + t]; su += w*asrc1[k]; sv += w*adst1[k]; }
      u1[t] = su; v1[t] = sv;
    }
    return;
  }
  { // compaction
    int* wtot = (int*)lds;
    int* woff = (int*)lds + 16;
    const int b = blk - 659;
    const int w = t >> 6, lane = t & 63;
    const int m = mask[(b << 10) + t];
    const u64 bal = __ballot(m != 0);
    const int pos = __popcll(bal & ((1ull << lane) - 1ull));
    if (lane == 0) wtot[w] = __popcll(bal);
    __syncthreads();
    if (t == 0) { int a = 0; for (int i = 0; i < 16; i++) { woff[i] = a; a += wtot[i]; } cnt[b] = a; }
    __syncthreads();
    if (m) idxb[(b << 10) + woff[w] + pos] = t;
  }
}

// ---- gather+normalize, and fused layer-0 als/ald (als = h.(W a_src) = h.u0) --
__global__ __launch_bounds__(256)
void hn_kernel(const float* __restrict__ hidden, const int* __restrict__ cnt,
               const int* __restrict__ idx,
               const float* __restrict__ u0, const float* __restrict__ v0,
               const float* __restrict__ aeb,
               u16* __restrict__ hnc, u16* __restrict__ hallc,
               float* __restrict__ als, float* __restrict__ ald)
{
  const int gr = blockIdx.x * 4 + (threadIdx.x >> 6);
  const int b = gr >> 10, c = gr & 1023;
  const int lane = threadIdx.x & 63;
  if (c >= cnt[b]) return;
  const int l = idx[gr];
  const float* h = hidden + (long)((b << 10) + l) * 768;
  float x[12]; float ss = 0.f, sa = 0.f, sd = 0.f;
#pragma unroll
  for (int k = 0; k < 12; k++) {
    x[k] = h[k*64 + lane];
    ss += x[k]*x[k];
    sa += x[k]*u0[k*64 + lane];
    sd += x[k]*v0[k*64 + lane];
  }
#pragma unroll
  for (int o = 32; o > 0; o >>= 1) {
    ss += __shfl_xor(ss, o, 64);
    sa += __shfl_xor(sa, o, 64);
    sd += __shfl_xor(sd, o, 64);
  }
  const float inv = 1.f / fmaxf(sqrtf(ss), 1e-8f);
  if (lane == 0) { als[gr] = sa; ald[gr] = sd + aeb[0]; }
#pragma unroll
  for (int k = 0; k < 12; k++) {
    hnc[(long)gr*768   + k*64 + lane] = f2bf(x[k] * inv);
    hallc[(long)gr*1024 + k*64 + lane] = f2bf(x[k]);
  }
}

// ------- bf16 NT GEMM, 64x64 tile, BK=64, double-buffered, XOR-swizzled -------
// MODE 0: adj-byte epilogue (sim > TAU, guarded to [0,cnt)^2)
// MODE 1: gT store  (out[(b*128+c)*1024 + l] = bf16(acc))
// MODE 2: fused scorer: scores[gi] += sum_j tanh(acc+S1b[j])*S2W[j] (atomic)
template<int MODE>
__global__ __launch_bounds__(256)
void gemm_nt(const u16* __restrict__ A, const u16* __restrict__ B,
             int lda, int ldb, int K, long sA, long sB,
             void* __restrict__ outp,
             const int* __restrict__ cnt,
             const float* __restrict__ bvec,
             const float* __restrict__ s2w,
             float* __restrict__ scoresp)
{
  __shared__ u16 lA[2][64*64];
  __shared__ u16 lB[2][64*64];
  __shared__ float sgrid[64];
  const int t = threadIdx.x;
  const int w = t >> 6, lane = t & 63;
  const int bz = blockIdx.z;
  const int i0 = blockIdx.y * 64, n0 = blockIdx.x * 64;
  int cb = 0;
  if (MODE == 0) {
    cb = cnt[bz];
    if (i0 >= cb || n0 >= cb) return;
  } else {
    if ((i0 & 1023) >= cnt[i0 >> 10]) return;
  }
  const u16* Ab = A + (long)bz * sA;
  const u16* Bb = B + (long)bz * sB;
  const int wr = w >> 1, wc = w & 1;
  const int srow = t >> 3, scg = t & 7;
  const int sc0 = ((scg ^ (srow & 7)) << 3);
  const long arow0 = (long)(i0 + srow) * lda, arow1 = (long)(i0 + srow + 32) * lda;
  const long brow0 = (long)(n0 + srow) * ldb, brow1 = (long)(n0 + srow + 32) * ldb;
  const int rA = lane & 15, kg = lane >> 4;
  const int sw = rA & 7;
  const int off0 = ((kg ^ sw) << 3);
  const int off1 = (((4 + kg) ^ sw) << 3);
  const int rowA0 = (wr*32 + rA) * 64, rowA1 = (wr*32 + 16 + rA) * 64;
  const int rowB0 = (wc*32 + rA) * 64, rowB1 = (wc*32 + 16 + rA) * 64;
  f32x4 acc[2][2] = {};

  auto stage = [&](int buf, int kt) {
    async_lds16(Ab + arow0 + kt + sc0, &lA[buf][t*8]);
    async_lds16(Ab + arow1 + kt + sc0, &lA[buf][2048 + t*8]);
    async_lds16(Bb + brow0 + kt + sc0, &lB[buf][t*8]);
    async_lds16(Bb + brow1 + kt + sc0, &lB[buf][2048 + t*8]);
  };
  auto compute = [&](int buf) {
    short8 a00 = *(const short8*)&lA[buf][rowA0 + off0];
    short8 a01 = *(const short8*)&lA[buf][rowA0 + off1];
    short8 a10 = *(const short8*)&lA[buf][rowA1 + off0];
    short8 a11 = *(const short8*)&lA[buf][rowA1 + off1];
    short8 b00 = *(const short8*)&lB[buf][rowB0 + off0];
    short8 b01 = *(const short8*)&lB[buf][rowB0 + off1];
    short8 b10 = *(const short8*)&lB[buf][rowB1 + off0];
    short8 b11 = *(const short8*)&lB[buf][rowB1 + off1];
    acc[0][0] = __builtin_amdgcn_mfma_f32_16x16x32_bf16(a00, b00, acc[0][0], 0, 0, 0);
    acc[0][1] = __builtin_amdgcn_mfma_f32_16x16x32_bf16(a00, b10, acc[0][1], 0, 0, 0);
    acc[1][0] = __builtin_amdgcn_mfma_f32_16x16x32_bf16(a10, b00, acc[1][0], 0, 0, 0);
    acc[1][1] = __builtin_amdgcn_mfma_f32_16x16x32_bf16(a10, b10, acc[1][1], 0, 0, 0);
    acc[0][0] = __builtin_amdgcn_mfma_f32_16x16x32_bf16(a01, b01, acc[0][0], 0, 0, 0);
    acc[0][1] = __builtin_amdgcn_mfma_f32_16x16x32_bf16(a01, b11, acc[0][1], 0, 0, 0);
    acc[1][0] = __builtin_amdgcn_mfma_f32_16x16x32_bf16(a11, b01, acc[1][0], 0, 0, 0);
    acc[1][1] = __builtin_amdgcn_mfma_f32_16x16x32_bf16(a11, b11, acc[1][1], 0, 0, 0);
  };

  const int nt = K >> 6;
  stage(0, 0);
  __syncthreads();
  int cur = 0;
  for (int kt = 1; kt < nt; kt++) {
    stage(cur ^ 1, kt << 6);
    compute(cur);
    __syncthreads();
    cur ^= 1;
  }
  compute(cur);

  if (MODE == 2) {
    if (t < 64) sgrid[t] = 0.f;
    __syncthreads();
#pragma unroll
    for (int m = 0; m < 2; m++)
#pragma unroll
      for (int r = 0; r < 4; r++) {
        const int rl = wr*32 + m*16 + kg*4 + r;
        float contrib = 0.f;
#pragma unroll
        for (int n = 0; n < 2; n++) {
          const int gj = n0 + wc*32 + n*16 + rA;
          contrib += tanhf(acc[m][n][r] + bvec[gj]) * s2w[gj];
        }
        atomicAdd(&sgrid[rl], contrib);
      }
    __syncthreads();
    if (t < 64) {
      const int gi = i0 + t;
      if ((gi & 1023) < cnt[gi >> 10]) atomicAdd(&scoresp[gi], sgrid[t]);
    }
    return;
  }

#pragma unroll
  for (int m = 0; m < 2; m++) {
    const int gi0 = i0 + wr*32 + m*16 + kg*4;
#pragma unroll
    for (int n = 0; n < 2; n++) {
      const int gj = n0 + wc*32 + n*16 + rA;
#pragma unroll
      for (int r = 0; r < 4; r++) {
        const int gi = gi0 + r;
        const float c = acc[m][n][r];
        if (MODE == 0) {
          if (gi < cb && gj < cb)
            ((unsigned char*)outp)[((long)bz << 20) + ((long)gi << 10) + gj] = (c > TAU_F) ? 1 : 0;
        } else {
          const int b = gi >> 10, l = gi & 1023;
          ((u16*)outp)[(((long)(b*128 + gj)) << 10) + l] = f2bf(c);
        }
      }
    }
  }
}

// ---------------- fused GAT attention, sparsity-skipping, compacted ----------
// Optionally fuses next-layer als/ald (= h1.u1 / h1.v1 + ae1) in the epilogue.
__global__ __launch_bounds__(256)
void gat_attn(const unsigned char* __restrict__ adj,
              const float* __restrict__ ald, const float* __restrict__ als,
              const u16* __restrict__ gT, const float* __restrict__ bias,
              const int* __restrict__ cnt,
              float* __restrict__ hf, u16* __restrict__ hall, int hall_off,
              const float* __restrict__ u1, const float* __restrict__ v1,
              const float* __restrict__ aeb1,
              float* __restrict__ als_o, float* __restrict__ ald_o)
{
  __shared__ float red[4][16][132];
  __shared__ float ssumw[4][16];
  __shared__ float alds[16][17], aldd[16][17];
  const int t = threadIdx.x, w = t >> 6, lane = t & 63;
  const int bz = blockIdx.y, i0 = blockIdx.x * 16;
  const int cb = cnt[bz];
  if (i0 >= cb) return;
  const int rr = lane & 15, kg = lane >> 4;
  const int r0 = i0 + rr;
  const bool rvalid = r0 < cb;
  const float ald0 = ald[(bz << 10) + r0];
  const unsigned char* arow = adj + ((long)bz << 20) + ((long)r0 << 10);
  const float* als_b = als + (bz << 10);
  const u16* gTb = gT + ((long)bz << 17);
  float s0 = 0.f;
  f32x4 acc[8] = {};
  const int jbase = w * 256 + kg * 8;

  u64 aw[8];
#pragma unroll
  for (int it = 0; it < 8; it++) {
    const int jl = jbase + it*32;
    u64 a = 0;
    if (rvalid && jl < cb) {
      a = *(const u64*)(arow + jl);
      const int rem = cb - jl;
      if (rem < 8) a &= (1ull << (rem * 8)) - 1ull;   // keep only cols < cb
    }
    aw[it] = a;
  }

#pragma unroll
  for (int it = 0; it < 8; it++) {
    const u64 a0 = aw[it];
    if (__any(a0 != 0ull)) {
      const int jl = jbase + it*32;
      const float4 f0 = *(const float4*)(als_b + jl);
      const float4 f1 = *(const float4*)(als_b + jl + 4);
      const float sv[8] = {f0.x, f0.y, f0.z, f0.w, f1.x, f1.y, f1.z, f1.w};
      short8 pa;
#pragma unroll
      for (int e = 0; e < 8; e++) {
        float x = ald0 + sv[e];
        x = x > 0.f ? x : 0.2f * x;
        const float p = ((a0 >> (8*e)) & 255ull) ? __expf(x) : 0.f;
        s0 += p;
        pa[e] = (short)f2bf(p);
      }
#pragma unroll
      for (int nf = 0; nf < 8; nf++) {
        const short8 b = *(const short8*)&gTb[(long)(nf*16 + rr) * 1024 + jl];
        acc[nf] = __builtin_amdgcn_mfma_f32_16x16x32_bf16(pa, b, acc[nf], 0, 0, 0);
      }
    }
  }

  s0 += __shfl_xor(s0, 16, 64);
  s0 += __shfl_xor(s0, 32, 64);
  if (lane < 16) ssumw[w][lane] = s0;
#pragma unroll
  for (int nf = 0; nf < 8; nf++)
#pragma unroll
    for (int rg = 0; rg < 4; rg++)
      red[w][kg*4 + rg][nf*16 + rr] = acc[nf][rg];
  __syncthreads();

  const int r = t >> 4, c0 = (t & 15) * 8;
  const float sm = ssumw[0][r] + ssumw[1][r] + ssumw[2][r] + ssumw[3][r];
  const float inv = sm > 0.f ? 1.f / sm : 0.f;
  const long gi = ((long)bz << 10) + i0 + r;
  float* hrow = hf + gi * 128;
  u16* orow = hall + gi * 1024 + hall_off;
  float pa_s = 0.f, pa_d = 0.f;
#pragma unroll
  for (int q = 0; q < 8; q++) {
    const int c = c0 + q;
    float v = (red[0][r][c] + red[1][r][c] + red[2][r][c] + red[3][r][c]) * inv + bias[c];
    v = v > 0.f ? v : 0.f;
    hrow[c] = v;
    orow[c] = f2bf(v);
    if (als_o) { pa_s += v * u1[c]; pa_d += v * v1[c]; }
  }
  if (als_o) {
    alds[r][t & 15] = pa_s;
    aldd[r][t & 15] = pa_d;
    __syncthreads();
    if (t < 16) {
      float s = 0.f, d = 0.f;
#pragma unroll
      for (int j = 0; j < 16; j++) { s += alds[t][j]; d += aldd[t][j]; }
      als_o[(bz << 10) + i0 + t] = s;
      ald_o[(bz << 10) + i0 + t] = d + aeb1[0];
    }
  }
}

// ---------------- pooled with inline masked softmax --------------------------
__global__ __launch_bounds__(256)
void pooled_kernel(const float* __restrict__ hidden, const float* __restrict__ h1f,
                   const float* __restrict__ h2f, const float* __restrict__ scores,
                   const int* __restrict__ cnt, const int* __restrict__ idx,
                   float* __restrict__ out)
{
  __shared__ float tot[4];
  const int b = blockIdx.y, l0 = blockIdx.x * 64, t = threadIdx.x;
  const int cb = cnt[b];
  if (l0 >= cb) return;
  // softmax denominator (recomputed per block; scores are L2-resident)
  float part = 0.f;
#pragma unroll
  for (int q = 0; q < 4; q++) {
    const int l = q*256 + t;
    if (l < cb) part += __expf(scores[(b << 10) + l]);
  }
#pragma unroll
  for (int o = 32; o > 0; o >>= 1) part += __shfl_xor(part, o, 64);
  if ((t & 63) == 0) tot[t >> 6] = part;
  __syncthreads();
  const float inv = 1.f / fmaxf(tot[0] + tot[1] + tot[2] + tot[3], 1e-16f);

  const int lim = min(64, cb - l0);
  float a0 = 0.f, a1 = 0.f, a2 = 0.f, a3 = 0.f;
  for (int l = 0; l < lim; l++) {
    const int gl = (b << 10) + l0 + l;
    const float wv = __expf(scores[gl]) * inv;
    const float* hr = hidden + (long)((b << 10) + idx[gl]) * 768;
    a0 += wv * hr[t];
    a1 += wv * hr[256 + t];
    a2 += wv * hr[512 + t];
    const float v3 = (t < 128) ? h1f[(long)gl*128 + t] : h2f[(long)gl*128 + (t - 128)];
    a3 += wv * v3;
  }
  atomicAdd(&out[(b<<10) + t],        a0);
  atomicAdd(&out[(b<<10) + 256 + t],  a1);
  atomicAdd(&out[(b<<10) + 512 + t],  a2);
  atomicAdd(&out[(b<<10) + 768 + t],  a3);
}

// ---------------- launch ----------------
extern "C" void kernel_launch(void* const* d_in, const int* in_sizes, int n_in,
                              void* d_out, int out_size, void* d_ws, size_t ws_size,
                              hipStream_t stream)
{
  const float* hidden = (const float*)d_in[0];
  const int*   mask   = (const int*)d_in[1];
  const float* W0     = (const float*)d_in[2];
  const float* asrc0  = (const float*)d_in[3];
  const float* adst0  = (const float*)d_in[4];
  const float* wed0   = (const float*)d_in[5];
  const float* aed0   = (const float*)d_in[6];
  const float* bias0  = (const float*)d_in[7];
  const float* W1     = (const float*)d_in[8];
  const float* asrc1  = (const float*)d_in[9];
  const float* adst1  = (const float*)d_in[10];
  const float* wed1   = (const float*)d_in[11];
  const float* aed1   = (const float*)d_in[12];
  const float* bias1  = (const float*)d_in[13];
  const float* S1W    = (const float*)d_in[14];
  const float* S1b    = (const float*)d_in[15];
  const float* S2W    = (const float*)d_in[16];
  // S2b (d_in[17]) is a uniform shift of all scores -> cancels in softmax.
  float* out = (float*)d_out;

  char* ws = (char*)d_ws;
  u16* hallc = (u16*)(ws + 0);                    // 16384x1024 bf16 compacted
  u16* hnc  = (u16*)(ws + 33554432);              // 16384x768 bf16 compacted
  unsigned char* adj = (unsigned char*)(ws + 58720256); // 16x1024x1024
  u16* gt   = (u16*)(ws + 75497472);              // 16x128x1024 bf16
  u16* w0t  = (u16*)(ws + 79691776);              // 128x768
  u16* w1t  = (u16*)(ws + 79888384);              // 128x128
  u16* s1t  = (u16*)(ws + 79921152);              // 512x1024
  float* ald = (float*)(ws + 80969728);           // 16x1024
  float* als = (float*)(ws + 81035264);           // 16x1024
  float* h1f = (float*)(ws + 81100800);           // 16x1024x128 f32
  float* h2f = (float*)(ws + 89489408);           // 16x1024x128 f32
  float* scores = (float*)(ws + 97878016);        // 16x1024
  float* als1   = (float*)(ws + 97943552);        // 16x1024
  float* ald1   = (float*)(ws + 98009088);        // 16x1024
  float* aeb    = (float*)(ws + 98074624);        // 2 floats
  int*   cnt    = (int*)(ws + 98075136);          // 16 ints
  int*   idxb   = (int*)(ws + 98075648);          // 16x1024 ints
  float* u0     = (float*)(ws + 98141184);        // 768
  float* v0     = (float*)(ws + 98144256);        // 768
  float* u1     = (float*)(ws + 98147328);        // 128
  float* v1     = (float*)(ws + 98147840);        // 128

  pre_kernel<<<675, 1024, 0, stream>>>(out, scores, W0, w0t, W1, w1t, S1W, s1t,
      wed0, aed0, wed1, aed1, aeb, asrc0, adst0, asrc1, adst1,
      u0, v0, u1, v1, mask, cnt, idxb);

  hn_kernel<<<4096, 256, 0, stream>>>(hidden, cnt, idxb, u0, v0, aeb, hnc, hallc, als, ald);

  // adjacency in compacted space
  gemm_nt<0><<<dim3(16,16,16), 256, 0, stream>>>(hnc, hnc, 768, 768, 768,
        (long)1024*768, (long)1024*768, adj, cnt, nullptr, nullptr, nullptr);

  // layer 0
  gemm_nt<1><<<dim3(2,256,1), 256, 0, stream>>>(hallc, w0t, 1024, 768, 768, 0, 0, gt, cnt, nullptr, nullptr, nullptr);
  gat_attn<<<dim3(64,16), 256, 0, stream>>>(adj, ald, als, gt, bias0, cnt, h1f, hallc, 768,
        u1, v1, aeb + 1, als1, ald1);

  // layer 1
  gemm_nt<1><<<dim3(2,256,1), 256, 0, stream>>>(hallc + 768, w1t, 1024, 128, 128, 0, 0, gt, cnt, nullptr, nullptr, nullptr);
  gat_attn<<<dim3(64,16), 256, 0, stream>>>(adj, ald1, als1, gt, bias1, cnt, h2f, hallc, 896,
        nullptr, nullptr, nullptr, nullptr, nullptr);

  // scorer (fused tanh + S2 dot -> scores atomics)
  gemm_nt<2><<<dim3(8,256,1), 256, 0, stream>>>(hallc, s1t, 1024, 1024, 1024, 0, 0, nullptr, cnt, S1b, S2W, scores);

  pooled_kernel<<<dim3(16,16), 256, 0, stream>>>(hidden, h1f, h2f, scores, cnt, idxb, out);
}

// Round 8
// 148.660 us; speedup vs baseline: 1.3611x; 1.2189x over previous
//
#include <hip/hip_runtime.h>

typedef __attribute__((ext_vector_type(8))) short short8;
typedef __attribute__((ext_vector_type(4))) float f32x4;
typedef unsigned short u16;
typedef unsigned int u32;
typedef unsigned long long u64;

#define TAU_F 0.3f

__device__ __forceinline__ u16 f2bf(float f){
  u32 u = __float_as_uint(f);
  u32 r = u + 0x7FFFu + ((u >> 16) & 1u);
  return (u16)(r >> 16);
}
__device__ __forceinline__ float bf2f(u16 v){
  return __uint_as_float(((u32)v) << 16);
}

typedef __attribute__((address_space(1))) const u32 glb_u32;
typedef __attribute__((address_space(3))) u32 lds_u32;
__device__ __forceinline__ void async_lds16(const void* g, void* l){
  __builtin_amdgcn_global_load_lds((glb_u32*)g, (lds_u32*)l, 16, 0, 0);
}

// ---------------- merged preprocessing (one launch) --------------------------
__global__ __launch_bounds__(1024)
void pre_kernel(float* __restrict__ out, float* __restrict__ scores,
                const float* __restrict__ W0, u16* __restrict__ w0t,
                const float* __restrict__ W1, u16* __restrict__ w1t,
                const float* __restrict__ S1W, u16* __restrict__ s1t,
                const float* __restrict__ wed0, const float* __restrict__ aed0,
                const float* __restrict__ wed1, const float* __restrict__ aed1,
                float* __restrict__ aeb,
                const float* __restrict__ asrc0, const float* __restrict__ adst0,
                const float* __restrict__ asrc1, const float* __restrict__ adst1,
                float* __restrict__ u0, float* __restrict__ v0,
                float* __restrict__ u1, float* __restrict__ v1,
                const int* __restrict__ mask, int* __restrict__ cnt, int* __restrict__ idxb)
{
  __shared__ float lds[1024];
  const int blk = blockIdx.x, t = threadIdx.x;
  if (blk < 16) { out[blk*1024 + t] = 0.f; return; }
  if (blk < 32) { scores[(blk-16)*1024 + t] = 0.f; return; }
  if (blk < 128) { const int i = (blk-32)*1024 + t; if (i < 98304) { const int k = i >> 7, n = i & 127; w0t[n*768 + k] = f2bf(W0[i]); } return; }
  if (blk < 144) { const int i = (blk-128)*1024 + t; const int k = i >> 7, n = i & 127; w1t[n*128 + k] = f2bf(W1[i]); return; }
  if (blk < 656) { const int i = (blk-144)*1024 + t; const int k = i >> 9, n = i & 511; s1t[n*1024 + k] = f2bf(S1W[i]); return; }
  if (blk == 656) {
    if (t < 128) { lds[t] = wed0[t]*aed0[t]; lds[128+t] = wed1[t]*aed1[t]; }
    __syncthreads();
    for (int o = 64; o > 0; o >>= 1) { if (t < o) { lds[t] += lds[t+o]; lds[128+t] += lds[128+t+o]; } __syncthreads(); }
    if (t == 0) { aeb[0] = lds[0]; aeb[1] = lds[128]; }
    return;
  }
  if (blk == 657) {
    if (t < 768) {
      float su = 0.f, sv = 0.f;
      for (int c = 0; c < 128; c++) { const float w = W0[t*128 + c]; su += w*asrc0[c]; sv += w*adst0[c]; }
      u0[t] = su; v0[t] = sv;
    }
    return;
  }
  if (blk == 658) {
    if (t < 128) {
      float su = 0.f, sv = 0.f;
      for (int k = 0; k < 128; k++) { const float w = W1[k*128 + t]; su += w*asrc1[k]; sv += w*adst1[k]; }
      u1[t] = su; v1[t] = sv;
    }
    return;
  }
  { // compaction
    int* wtot = (int*)lds;
    int* woff = (int*)lds + 16;
    const int b = blk - 659;
    const int w = t >> 6, lane = t & 63;
    const int m = mask[(b << 10) + t];
    const u64 bal = __ballot(m != 0);
    const int pos = __popcll(bal & ((1ull << lane) - 1ull));
    if (lane == 0) wtot[w] = __popcll(bal);
    __syncthreads();
    if (t == 0) { int a = 0; for (int i = 0; i < 16; i++) { woff[i] = a; a += wtot[i]; } cnt[b] = a; }
    __syncthreads();
    if (m) idxb[(b << 10) + woff[w] + pos] = t;
  }
}

// ---- gather+normalize, fused layer-0 als/ald --------------------------------
__global__ __launch_bounds__(256)
void hn_kernel(const float* __restrict__ hidden, const int* __restrict__ cnt,
               const int* __restrict__ idx,
               const float* __restrict__ u0, const float* __restrict__ v0,
               const float* __restrict__ aeb,
               u16* __restrict__ hnc, u16* __restrict__ hallc,
               float* __restrict__ als, float* __restrict__ ald)
{
  const int gr = blockIdx.x * 4 + (threadIdx.x >> 6);
  const int b = gr >> 10, c = gr & 1023;
  const int lane = threadIdx.x & 63;
  if (c >= cnt[b]) return;
  const int l = idx[gr];
  const float* h = hidden + (long)((b << 10) + l) * 768;
  float x[12]; float ss = 0.f, sa = 0.f, sd = 0.f;
#pragma unroll
  for (int k = 0; k < 12; k++) {
    x[k] = h[k*64 + lane];
    ss += x[k]*x[k];
    sa += x[k]*u0[k*64 + lane];
    sd += x[k]*v0[k*64 + lane];
  }
#pragma unroll
  for (int o = 32; o > 0; o >>= 1) {
    ss += __shfl_xor(ss, o, 64);
    sa += __shfl_xor(sa, o, 64);
    sd += __shfl_xor(sd, o, 64);
  }
  const float inv = 1.f / fmaxf(sqrtf(ss), 1e-8f);
  if (lane == 0) { als[gr] = sa; ald[gr] = sd + aeb[0]; }
#pragma unroll
  for (int k = 0; k < 12; k++) {
    hnc[(long)gr*768   + k*64 + lane] = f2bf(x[k] * inv);
    hallc[(long)gr*1024 + k*64 + lane] = f2bf(x[k]);
  }
}

// ------- bf16 NT GEMM, 64x64 tile, BK=64, dbuf, XOR-swizzled, XCD-pinned -----
// MODE 0: flat grid 4096; batch bz pinned to XCD bz>>1 (tiles share panels)
// MODE 1: 2D grid (x, yrow)
// MODE 2: flat grid 2048; row-panel y pinned to XCD y&7 (8 x-tiles share A)
template<int MODE>
__global__ __launch_bounds__(256)
void gemm_nt(const u16* __restrict__ A, const u16* __restrict__ B,
             int lda, int ldb, int K, long sA, long sB,
             void* __restrict__ outp,
             const int* __restrict__ cnt,
             const float* __restrict__ bvec,
             const float* __restrict__ s2w,
             float* __restrict__ scoresp)
{
  __shared__ u16 lA[2][64*64];
  __shared__ u16 lB[2][64*64];
  __shared__ float sgrid[64];
  const int t = threadIdx.x;
  const int w = t >> 6, lane = t & 63;
  int bz, i0, n0, cb = 0;
  if (MODE == 0) {
    const int o = blockIdx.x;            // 4096 = 8 xcd * 512
    const int xcd = o & 7, s = o >> 3;   // s: 0..511
    bz = xcd*2 + (s >> 8);               // 2 batches per XCD
    const int tile = s & 255;
    i0 = (tile >> 4) * 64; n0 = (tile & 15) * 64;
    cb = cnt[bz];
    if (i0 >= cb || n0 >= cb) return;
  } else if (MODE == 2) {
    const int o = blockIdx.x;            // 2048 = 256 y * 8 x
    const int y = (o & 7) + ((o >> 6) << 3);
    const int x = (o >> 3) & 7;
    i0 = y * 64; n0 = x * 64;
    bz = 0;
    if ((i0 & 1023) >= cnt[i0 >> 10]) return;
  } else {
    bz = 0;
    i0 = blockIdx.y * 64; n0 = blockIdx.x * 64;
    if ((i0 & 1023) >= cnt[i0 >> 10]) return;
  }
  const u16* Ab = A + (long)bz * sA;
  const u16* Bb = B + (long)bz * sB;
  const int wr = w >> 1, wc = w & 1;
  const int srow = t >> 3, scg = t & 7;
  const int sc0 = ((scg ^ (srow & 7)) << 3);
  const long arow0 = (long)(i0 + srow) * lda, arow1 = (long)(i0 + srow + 32) * lda;
  const long brow0 = (long)(n0 + srow) * ldb, brow1 = (long)(n0 + srow + 32) * ldb;
  const int rA = lane & 15, kg = lane >> 4;
  const int sw = rA & 7;
  const int off0 = ((kg ^ sw) << 3);
  const int off1 = (((4 + kg) ^ sw) << 3);
  const int rowA0 = (wr*32 + rA) * 64, rowA1 = (wr*32 + 16 + rA) * 64;
  const int rowB0 = (wc*32 + rA) * 64, rowB1 = (wc*32 + 16 + rA) * 64;
  f32x4 acc[2][2] = {};

  auto stage = [&](int buf, int kt) {
    async_lds16(Ab + arow0 + kt + sc0, &lA[buf][t*8]);
    async_lds16(Ab + arow1 + kt + sc0, &lA[buf][2048 + t*8]);
    async_lds16(Bb + brow0 + kt + sc0, &lB[buf][t*8]);
    async_lds16(Bb + brow1 + kt + sc0, &lB[buf][2048 + t*8]);
  };
  auto compute = [&](int buf) {
    short8 a00 = *(const short8*)&lA[buf][rowA0 + off0];
    short8 a01 = *(const short8*)&lA[buf][rowA0 + off1];
    short8 a10 = *(const short8*)&lA[buf][rowA1 + off0];
    short8 a11 = *(const short8*)&lA[buf][rowA1 + off1];
    short8 b00 = *(const short8*)&lB[buf][rowB0 + off0];
    short8 b01 = *(const short8*)&lB[buf][rowB0 + off1];
    short8 b10 = *(const short8*)&lB[buf][rowB1 + off0];
    short8 b11 = *(const short8*)&lB[buf][rowB1 + off1];
    acc[0][0] = __builtin_amdgcn_mfma_f32_16x16x32_bf16(a00, b00, acc[0][0], 0, 0, 0);
    acc[0][1] = __builtin_amdgcn_mfma_f32_16x16x32_bf16(a00, b10, acc[0][1], 0, 0, 0);
    acc[1][0] = __builtin_amdgcn_mfma_f32_16x16x32_bf16(a10, b00, acc[1][0], 0, 0, 0);
    acc[1][1] = __builtin_amdgcn_mfma_f32_16x16x32_bf16(a10, b10, acc[1][1], 0, 0, 0);
    acc[0][0] = __builtin_amdgcn_mfma_f32_16x16x32_bf16(a01, b01, acc[0][0], 0, 0, 0);
    acc[0][1] = __builtin_amdgcn_mfma_f32_16x16x32_bf16(a01, b11, acc[0][1], 0, 0, 0);
    acc[1][0] = __builtin_amdgcn_mfma_f32_16x16x32_bf16(a11, b01, acc[1][0], 0, 0, 0);
    acc[1][1] = __builtin_amdgcn_mfma_f32_16x16x32_bf16(a11, b11, acc[1][1], 0, 0, 0);
  };

  const int nt = K >> 6;
  stage(0, 0);
  __syncthreads();
  int cur = 0;
  for (int kt = 1; kt < nt; kt++) {
    stage(cur ^ 1, kt << 6);
    compute(cur);
    __syncthreads();
    cur ^= 1;
  }
  compute(cur);

  if (MODE == 2) {
    if (t < 64) sgrid[t] = 0.f;
    __syncthreads();
#pragma unroll
    for (int m = 0; m < 2; m++)
#pragma unroll
      for (int r = 0; r < 4; r++) {
        const int rl = wr*32 + m*16 + kg*4 + r;
        float contrib = 0.f;
#pragma unroll
        for (int n = 0; n < 2; n++) {
          const int gj = n0 + wc*32 + n*16 + rA;
          contrib += tanhf(acc[m][n][r] + bvec[gj]) * s2w[gj];
        }
        // reduce across the 16 rA lanes of this k-group, then one atomic
#pragma unroll
        for (int off = 1; off < 16; off <<= 1) contrib += __shfl_xor(contrib, off, 64);
        if (rA == 0) atomicAdd(&sgrid[rl], contrib);
      }
    __syncthreads();
    if (t < 64) {
      const int gi = i0 + t;
      if ((gi & 1023) < cnt[gi >> 10]) atomicAdd(&scoresp[gi], sgrid[t]);
    }
    return;
  }

#pragma unroll
  for (int m = 0; m < 2; m++) {
    const int gi0 = i0 + wr*32 + m*16 + kg*4;
#pragma unroll
    for (int n = 0; n < 2; n++) {
      const int gj = n0 + wc*32 + n*16 + rA;
#pragma unroll
      for (int r = 0; r < 4; r++) {
        const int gi = gi0 + r;
        const float c = acc[m][n][r];
        if (MODE == 0) {
          if (gi < cb && gj < cb)
            ((unsigned char*)outp)[((long)bz << 20) + ((long)gi << 10) + gj] = (c > TAU_F) ? 1 : 0;
        } else {
          const int b = gi >> 10, l = gi & 1023;
          ((u16*)outp)[(((long)(b*128 + gj)) << 10) + l] = f2bf(c);
        }
      }
    }
  }
}

// ---------------- fused GAT attention, sparsity-skipping, XCD-pinned ---------
__global__ __launch_bounds__(256)
void gat_attn(const unsigned char* __restrict__ adj,
              const float* __restrict__ ald, const float* __restrict__ als,
              const u16* __restrict__ gT, const float* __restrict__ bias,
              const int* __restrict__ cnt,
              float* __restrict__ hf, u16* __restrict__ hall, int hall_off,
              const float* __restrict__ u1, const float* __restrict__ v1,
              const float* __restrict__ aeb1,
              float* __restrict__ als_o, float* __restrict__ ald_o)
{
  __shared__ float red[4][16][132];
  __shared__ float ssumw[4][16];
  __shared__ float alds[16][17], aldd[16][17];
  const int t = threadIdx.x, w = t >> 6, lane = t & 63;
  // flat grid 1024: batch bz pinned to XCD bz>>1
  const int o = blockIdx.x;
  const int xcd = o & 7, s = o >> 3;               // s: 0..127
  const int bz = xcd*2 + (s >> 6);
  const int i0 = (s & 63) * 16;
  const int cb = cnt[bz];
  if (i0 >= cb) return;
  const int rr = lane & 15, kg = lane >> 4;
  const int r0 = i0 + rr;
  const bool rvalid = r0 < cb;
  const float ald0 = ald[(bz << 10) + r0];
  const unsigned char* arow = adj + ((long)bz << 20) + ((long)r0 << 10);
  const float* als_b = als + (bz << 10);
  const u16* gTb = gT + ((long)bz << 17);
  float s0 = 0.f;
  f32x4 acc[8] = {};
  const int jbase = w * 256 + kg * 8;

  u64 aw[8];
#pragma unroll
  for (int it = 0; it < 8; it++) {
    const int jl = jbase + it*32;
    u64 a = 0;
    if (rvalid && jl < cb) {
      a = *(const u64*)(arow + jl);
      const int rem = cb - jl;
      if (rem < 8) a &= (1ull << (rem * 8)) - 1ull;
    }
    aw[it] = a;
  }

#pragma unroll
  for (int it = 0; it < 8; it++) {
    const u64 a0 = aw[it];
    if (__any(a0 != 0ull)) {
      const int jl = jbase + it*32;
      const float4 f0 = *(const float4*)(als_b + jl);
      const float4 f1 = *(const float4*)(als_b + jl + 4);
      const float sv[8] = {f0.x, f0.y, f0.z, f0.w, f1.x, f1.y, f1.z, f1.w};
      short8 pa;
#pragma unroll
      for (int e = 0; e < 8; e++) {
        float x = ald0 + sv[e];
        x = x > 0.f ? x : 0.2f * x;
        const float p = ((a0 >> (8*e)) & 255ull) ? __expf(x) : 0.f;
        s0 += p;
        pa[e] = (short)f2bf(p);
      }
#pragma unroll
      for (int nf = 0; nf < 8; nf++) {
        const short8 b = *(const short8*)&gTb[(long)(nf*16 + rr) * 1024 + jl];
        acc[nf] = __builtin_amdgcn_mfma_f32_16x16x32_bf16(pa, b, acc[nf], 0, 0, 0);
      }
    }
  }

  s0 += __shfl_xor(s0, 16, 64);
  s0 += __shfl_xor(s0, 32, 64);
  if (lane < 16) ssumw[w][lane] = s0;
#pragma unroll
  for (int nf = 0; nf < 8; nf++)
#pragma unroll
    for (int rg = 0; rg < 4; rg++)
      red[w][kg*4 + rg][nf*16 + rr] = acc[nf][rg];
  __syncthreads();

  const int r = t >> 4, c0 = (t & 15) * 8;
  const float sm = ssumw[0][r] + ssumw[1][r] + ssumw[2][r] + ssumw[3][r];
  const float inv = sm > 0.f ? 1.f / sm : 0.f;
  const long gi = ((long)bz << 10) + i0 + r;
  float* hrow = hf + gi * 128;
  u16* orow = hall + gi * 1024 + hall_off;
  float pa_s = 0.f, pa_d = 0.f;
#pragma unroll
  for (int q = 0; q < 8; q++) {
    const int c = c0 + q;
    float v = (red[0][r][c] + red[1][r][c] + red[2][r][c] + red[3][r][c]) * inv + bias[c];
    v = v > 0.f ? v : 0.f;
    hrow[c] = v;
    orow[c] = f2bf(v);
    if (als_o) { pa_s += v * u1[c]; pa_d += v * v1[c]; }
  }
  if (als_o) {
    alds[r][t & 15] = pa_s;
    aldd[r][t & 15] = pa_d;
    __syncthreads();
    if (t < 16) {
      float s2 = 0.f, d2 = 0.f;
#pragma unroll
      for (int j = 0; j < 16; j++) { s2 += alds[t][j]; d2 += aldd[t][j]; }
      als_o[(bz << 10) + i0 + t] = s2;
      ald_o[(bz << 10) + i0 + t] = d2 + aeb1[0];
    }
  }
}

// ---------------- pooled with inline masked softmax --------------------------
__global__ __launch_bounds__(256)
void pooled_kernel(const float* __restrict__ hidden, const float* __restrict__ h1f,
                   const float* __restrict__ h2f, const float* __restrict__ scores,
                   const int* __restrict__ cnt, const int* __restrict__ idx,
                   float* __restrict__ out)
{
  __shared__ float tot[4];
  const int b = blockIdx.y, l0 = blockIdx.x * 64, t = threadIdx.x;
  const int cb = cnt[b];
  if (l0 >= cb) return;
  float part = 0.f;
#pragma unroll
  for (int q = 0; q < 4; q++) {
    const int l = q*256 + t;
    if (l < cb) part += __expf(scores[(b << 10) + l]);
  }
#pragma unroll
  for (int o = 32; o > 0; o >>= 1) part += __shfl_xor(part, o, 64);
  if ((t & 63) == 0) tot[t >> 6] = part;
  __syncthreads();
  const float inv = 1.f / fmaxf(tot[0] + tot[1] + tot[2] + tot[3], 1e-16f);

  const int lim = min(64, cb - l0);
  float a0 = 0.f, a1 = 0.f, a2 = 0.f, a3 = 0.f;
  for (int l = 0; l < lim; l++) {
    const int gl = (b << 10) + l0 + l;
    const float wv = __expf(scores[gl]) * inv;
    const float* hr = hidden + (long)((b << 10) + idx[gl]) * 768;
    a0 += wv * hr[t];
    a1 += wv * hr[256 + t];
    a2 += wv * hr[512 + t];
    const float v3 = (t < 128) ? h1f[(long)gl*128 + t] : h2f[(long)gl*128 + (t - 128)];
    a3 += wv * v3;
  }
  atomicAdd(&out[(b<<10) + t],        a0);
  atomicAdd(&out[(b<<10) + 256 + t],  a1);
  atomicAdd(&out[(b<<10) + 512 + t],  a2);
  atomicAdd(&out[(b<<10) + 768 + t],  a3);
}

// ---------------- launch ----------------
extern "C" void kernel_launch(void* const* d_in, const int* in_sizes, int n_in,
                              void* d_out, int out_size, void* d_ws, size_t ws_size,
                              hipStream_t stream)
{
  const float* hidden = (const float*)d_in[0];
  const int*   mask   = (const int*)d_in[1];
  const float* W0     = (const float*)d_in[2];
  const float* asrc0  = (const float*)d_in[3];
  const float* adst0  = (const float*)d_in[4];
  const float* wed0   = (const float*)d_in[5];
  const float* aed0   = (const float*)d_in[6];
  const float* bias0  = (const float*)d_in[7];
  const float* W1     = (const float*)d_in[8];
  const float* asrc1  = (const float*)d_in[9];
  const float* adst1  = (const float*)d_in[10];
  const float* wed1   = (const float*)d_in[11];
  const float* aed1   = (const float*)d_in[12];
  const float* bias1  = (const float*)d_in[13];
  const float* S1W    = (const float*)d_in[14];
  const float* S1b    = (const float*)d_in[15];
  const float* S2W    = (const float*)d_in[16];
  // S2b cancels in softmax.
  float* out = (float*)d_out;

  char* ws = (char*)d_ws;
  u16* hallc = (u16*)(ws + 0);
  u16* hnc  = (u16*)(ws + 33554432);
  unsigned char* adj = (unsigned char*)(ws + 58720256);
  u16* gt   = (u16*)(ws + 75497472);
  u16* w0t  = (u16*)(ws + 79691776);
  u16* w1t  = (u16*)(ws + 79888384);
  u16* s1t  = (u16*)(ws + 79921152);
  float* ald = (float*)(ws + 80969728);
  float* als = (float*)(ws + 81035264);
  float* h1f = (float*)(ws + 81100800);
  float* h2f = (float*)(ws + 89489408);
  float* scores = (float*)(ws + 97878016);
  float* als1   = (float*)(ws + 97943552);
  float* ald1   = (float*)(ws + 98009088);
  float* aeb    = (float*)(ws + 98074624);
  int*   cnt    = (int*)(ws + 98075136);
  int*   idxb   = (int*)(ws + 98075648);
  float* u0     = (float*)(ws + 98141184);
  float* v0     = (float*)(ws + 98144256);
  float* u1     = (float*)(ws + 98147328);
  float* v1     = (float*)(ws + 98147840);

  pre_kernel<<<675, 1024, 0, stream>>>(out, scores, W0, w0t, W1, w1t, S1W, s1t,
      wed0, aed0, wed1, aed1, aeb, asrc0, adst0, asrc1, adst1,
      u0, v0, u1, v1, mask, cnt, idxb);

  hn_kernel<<<4096, 256, 0, stream>>>(hidden, cnt, idxb, u0, v0, aeb, hnc, hallc, als, ald);

  // adjacency in compacted space (XCD-pinned flat grid)
  gemm_nt<0><<<4096, 256, 0, stream>>>(hnc, hnc, 768, 768, 768,
        (long)1024*768, (long)1024*768, adj, cnt, nullptr, nullptr, nullptr);

  // layer 0
  gemm_nt<1><<<dim3(2,256,1), 256, 0, stream>>>(hallc, w0t, 1024, 768, 768, 0, 0, gt, cnt, nullptr, nullptr, nullptr);
  gat_attn<<<1024, 256, 0, stream>>>(adj, ald, als, gt, bias0, cnt, h1f, hallc, 768,
        u1, v1, aeb + 1, als1, ald1);

  // layer 1
  gemm_nt<1><<<dim3(2,256,1), 256, 0, stream>>>(hallc + 768, w1t, 1024, 128, 128, 0, 0, gt, cnt, nullptr, nullptr, nullptr);
  gat_attn<<<1024, 256, 0, stream>>>(adj, ald1, als1, gt, bias1, cnt, h2f, hallc, 896,
        nullptr, nullptr, nullptr, nullptr, nullptr);

  // scorer (fused tanh + S2 dot -> scores atomics; XCD-pinned flat grid)
  gemm_nt<2><<<2048, 256, 0, stream>>>(hallc, s1t, 1024, 1024, 1024, 0, 0, nullptr, cnt, S1b, S2W, scores);

  pooled_kernel<<<dim3(16,16), 256, 0, stream>>>(hidden, h1f, h2f, scores, cnt, idxb, out);
}